// Round 6
// baseline (1380.889 us; speedup 1.0000x reference)
//
#include <hip/hip_runtime.h>
#include <math.h>

// Problem dims
#define H_   192
#define W_   192
#define C_   128
#define CS_  24

// branch 0 (m1)
#define DM0  32
#define DI0  64
#define L0   2304
#define LT0  2305
#define NS0  64

// branches 1+2 (m2, shared weights) run as 128 sequences
#define DM2  24
#define DI2  48
#define L12  3072
#define LT12 3073
#define NS12 128

#define DST  16
#define NCHUNK 32
#define CL0  ((LT0 + NCHUNK - 1) / NCHUNK)    // 73
#define CL12 ((LT12 + NCHUNK - 1) / NCHUNK)   // 97

__device__ __forceinline__ float sigmoidf_(float x){ return 1.f/(1.f+__expf(-x)); }
__device__ __forceinline__ float siluf_(float x){ return x*sigmoidf_(x); }
__device__ __forceinline__ float softplusf_(float x){ return (x > 20.f) ? x : log1pf(__expf(x)); }

#define LD4(p)  (*(const float4*)(p))
#define ST4(p,v) (*(float4*)(p) = (v))

// ======== front: gather+LN+in_proj+conv+silu+x_proj+dt+scan1-compose ========
// one block (256 thr) per (local seq, chunk). CL+3 divisible by 4 for both branches.
template<int DM, int DI, int LT, int CL, int BID>
__global__ __launch_bounds__(256) void front(
    const float* __restrict__ x, const float* __restrict__ gt,
    const float* __restrict__ nw, const float* __restrict__ nb,
    const float* __restrict__ win, const float* __restrict__ cw,
    const float* __restrict__ cb, const float* __restrict__ xpw,
    const float* __restrict__ dtw, const float* __restrict__ dtb,
    const float* __restrict__ Alog,
    float* __restrict__ XS, float* __restrict__ DT,
    float* __restrict__ Bb, float* __restrict__ Cb, float* __restrict__ GATE,
    float* __restrict__ PRD, float* __restrict__ ACC, int seq0)
{
  constexpr int NR  = CL + 3;                 // 76 / 100 (both %4 == 0)
  constexpr int R3A = DM*2*DI;                // wintT [DM rows... stored [k][col]]
  constexpr int R3B = NR*36 + DI*36;          // dbl [NR][36] + xpwT [DI][36]
  constexpr int R3  = (R3A > R3B) ? R3A : R3B;
  __shared__ __align__(16) float smem[2*NR*DI + R3];
  float* xsin  = smem;                        // [NR][DI]; phase5+: dtl overlay
  float* dtl   = smem;
  float* xsc   = smem + NR*DI;                // [NR][DI]; phase1-2: xn [NR][DM]
  float* xn    = xsc;
  float* r3    = smem + 2*NR*DI;
  float* wintT = r3;                          // [DM][2*DI]  (k-major)
  float* dbl   = r3;                          // [NR][36]: B at 0..15, dt at 32,33
  float* xpwT  = r3 + NR*36;                  // [DI][36]   (k-major, o in [0,34))

  const int tid = threadIdx.x;
  const int sc = blockIdx.x / NCHUNK, c = blockIdx.x % NCHUNK;
  const int gid = seq0 + sc;
  const int t0 = c*CL;
  int nt = LT - t0; if (nt > CL) nt = CL;

  // stage wintT[k][col] = win[col*DM + k]
  for (int i = tid; i < DM*2*DI; i += 256) {
    int k = i / (2*DI), col = i - k*(2*DI);
    wintT[i] = win[col*DM + k];
  }
  // phase 1: gather + LN -> xn (full NR rows, zero outside sequence)
  {
    int hw = tid >> 5, dm = tid & 31;
    for (int r = hw; r < NR; r += 8) {
      int t = t0 - 3 + r;
      bool inr = (t >= 0 && t < LT);
      float v = 0.f;
      if (inr && dm < DM) {
        if (t == 0) v = gt[dm];
        else {
          int s = t - 1;
          if (BID == 0) {
            int p = s / 48, q = s - p*48;
            int cc = dm*4 + (p&1)*2 + (q&1);
            int ii = p >> 1, jj = q >> 1;
            v = x[cc*(H_*W_) + ((gid>>3)*CS_ + ii)*W_ + (gid&7)*CS_ + jj];
          } else {
            int cc = s / 24, rr = s - cc*24;
            int n = gid & 63, br = gid >> 6;
            int ii = br ? rr : dm;
            int jj = br ? dm : rr;
            v = x[cc*(H_*W_) + ((n>>3)*CS_ + ii)*W_ + (n&7)*CS_ + jj];
          }
        }
      }
      float s1 = (dm < DM) ? v : 0.f;
      float s2 = s1*s1;
      #pragma unroll
      for (int off = 1; off < 32; off <<= 1) {
        s1 += __shfl_xor(s1, off);
        s2 += __shfl_xor(s2, off);
      }
      if (dm < DM) {
        float mean = s1 * (1.f/DM);
        float var = s2 * (1.f/DM) - mean*mean;
        float xv = (v - mean)*rsqrtf(var + 1e-5f)*nw[dm] + nb[dm];
        xn[r*DM + dm] = inr ? xv : 0.f;
      }
    }
  }
  __syncthreads();
  // phase 2: in_proj, 4x4 register tiles; xs -> xsin, z -> GATE=silu(z)
  {
    constexpr int CT = (2*DI)/4;
    constexpr int RT = NR/4;
    for (int tile = tid; tile < RT*CT; tile += 256) {
      int r0 = (tile / CT)*4, c0 = (tile % CT)*4;
      float acc[4][4] = {};
      #pragma unroll
      for (int kq = 0; kq < DM/4; kq++) {
        float4 xr[4], wc[4];
        #pragma unroll
        for (int rr = 0; rr < 4; rr++) xr[rr] = LD4(xn + (r0+rr)*DM + kq*4);
        #pragma unroll
        for (int e = 0; e < 4; e++) wc[e] = LD4(wintT + (kq*4+e)*(2*DI) + c0);
        #pragma unroll
        for (int rr = 0; rr < 4; rr++) {
          acc[rr][0] += xr[rr].x*wc[0].x + xr[rr].y*wc[1].x + xr[rr].z*wc[2].x + xr[rr].w*wc[3].x;
          acc[rr][1] += xr[rr].x*wc[0].y + xr[rr].y*wc[1].y + xr[rr].z*wc[2].y + xr[rr].w*wc[3].y;
          acc[rr][2] += xr[rr].x*wc[0].z + xr[rr].y*wc[1].z + xr[rr].z*wc[2].z + xr[rr].w*wc[3].z;
          acc[rr][3] += xr[rr].x*wc[0].w + xr[rr].y*wc[1].w + xr[rr].z*wc[2].w + xr[rr].w*wc[3].w;
        }
      }
      if (c0 < DI) {
        #pragma unroll
        for (int rr = 0; rr < 4; rr++)
          ST4(xsin + (r0+rr)*DI + c0, make_float4(acc[rr][0],acc[rr][1],acc[rr][2],acc[rr][3]));
      } else {
        #pragma unroll
        for (int rr = 0; rr < 4; rr++) {
          int lt = r0 + rr - 3;
          if (lt >= 0 && lt < nt) {
            size_t tb = (size_t)sc*LT + t0 + lt;
            ST4(GATE + tb*DI + (c0-DI),
                make_float4(siluf_(acc[rr][0]),siluf_(acc[rr][1]),siluf_(acc[rr][2]),siluf_(acc[rr][3])));
          }
        }
      }
    }
  }
  __syncthreads();
  // phase 3: conv+silu -> xsc (+XS), zero-fill rows >= nt; stage xpwT
  for (int idx = tid; idx < NR*(DI/4); idx += 256) {
    int lt = idx / (DI/4), dq = idx - lt*(DI/4);
    int d0 = dq*4;
    float4 o = make_float4(0.f,0.f,0.f,0.f);
    if (lt < nt) {
      float4 a0 = LD4(xsin + (lt+0)*DI + d0);
      float4 a1 = LD4(xsin + (lt+1)*DI + d0);
      float4 a2 = LD4(xsin + (lt+2)*DI + d0);
      float4 a3 = LD4(xsin + (lt+3)*DI + d0);
      float4 w0 = LD4(cw + (d0+0)*4);
      float4 w1 = LD4(cw + (d0+1)*4);
      float4 w2 = LD4(cw + (d0+2)*4);
      float4 w3 = LD4(cw + (d0+3)*4);
      float4 cbq = LD4(cb + d0);
      o.x = siluf_(cbq.x + w0.x*a0.x + w0.y*a1.x + w0.z*a2.x + w0.w*a3.x);
      o.y = siluf_(cbq.y + w1.x*a0.y + w1.y*a1.y + w1.z*a2.y + w1.w*a3.y);
      o.z = siluf_(cbq.z + w2.x*a0.z + w2.y*a1.z + w2.z*a2.z + w2.w*a3.z);
      o.w = siluf_(cbq.w + w3.x*a0.w + w3.y*a1.w + w3.z*a2.w + w3.w*a3.w);
      ST4(XS + ((size_t)sc*LT + t0 + lt)*DI + d0, o);
    }
    ST4(xsc + lt*DI + d0, o);
  }
  for (int i = tid; i < DI*36; i += 256) {
    int k = i / 36, o = i - k*36;
    xpwT[i] = (o < 34) ? xpw[o*DI + k] : 0.f;
  }
  __syncthreads();
  // phase 4: x_proj 4x4 tiles -> dbl (B at 0..15, dt at 32,33) + Bb/Cb global
  {
    constexpr int RT = NR/4;
    for (int tile = tid; tile < RT*9; tile += 256) {
      int lt0 = (tile / 9)*4, o0 = (tile % 9)*4;
      float acc[4][4] = {};
      #pragma unroll
      for (int kq = 0; kq < DI/4; kq++) {
        float4 xq[4], wq[4];
        #pragma unroll
        for (int rr = 0; rr < 4; rr++) xq[rr] = LD4(xsc + (lt0+rr)*DI + kq*4);
        #pragma unroll
        for (int e = 0; e < 4; e++) wq[e] = LD4(xpwT + (kq*4+e)*36 + o0);
        #pragma unroll
        for (int rr = 0; rr < 4; rr++) {
          acc[rr][0] += xq[rr].x*wq[0].x + xq[rr].y*wq[1].x + xq[rr].z*wq[2].x + xq[rr].w*wq[3].x;
          acc[rr][1] += xq[rr].x*wq[0].y + xq[rr].y*wq[1].y + xq[rr].z*wq[2].y + xq[rr].w*wq[3].y;
          acc[rr][2] += xq[rr].x*wq[0].z + xq[rr].y*wq[1].z + xq[rr].z*wq[2].z + xq[rr].w*wq[3].z;
          acc[rr][3] += xq[rr].x*wq[0].w + xq[rr].y*wq[1].w + xq[rr].z*wq[2].w + xq[rr].w*wq[3].w;
        }
      }
      #pragma unroll
      for (int rr = 0; rr < 4; rr++) {
        int lt = lt0 + rr;
        if (lt < nt) {
          size_t tb = (size_t)sc*LT + t0 + lt;
          #pragma unroll
          for (int cc = 0; cc < 4; cc++) {
            int o = o0 + cc;
            float v = acc[rr][cc];
            if (o < 2)        dbl[lt*36 + 32 + o] = v;
            else if (o < 18) { dbl[lt*36 + (o-2)] = v; Bb[tb*DST + (o-2)] = v; }
            else if (o < 34)  Cb[tb*DST + (o-18)] = v;
          }
        }
      }
    }
  }
  __syncthreads();
  // phase 5: dt -> dtl (overlays xsin) + DT
  for (int idx = tid; idx < nt*(DI/4); idx += 256) {
    int lt = idx / (DI/4), dq = idx - lt*(DI/4);
    int d0 = dq*4;
    float t0v = dbl[lt*36 + 32], t1v = dbl[lt*36 + 33];
    float4 w0 = LD4(dtw + 2*d0);
    float4 w1 = LD4(dtw + 2*d0 + 4);
    float4 b4 = LD4(dtb + d0);
    float4 r;
    r.x = softplusf_(t0v*w0.x + t1v*w0.y + b4.x);
    r.y = softplusf_(t0v*w0.z + t1v*w0.w + b4.y);
    r.z = softplusf_(t0v*w1.x + t1v*w1.y + b4.z);
    r.w = softplusf_(t0v*w1.z + t1v*w1.w + b4.w);
    ST4(dtl + lt*DI + d0, r);
    ST4(DT + ((size_t)sc*LT + t0 + lt)*DI + d0, r);
  }
  __syncthreads();
  // phase 6: chunk composition, thread = (d, state-quad)
  for (int p = tid; p < DI*4; p += 256) {
    int d = p >> 2, iq = p & 3;
    float4 al = LD4(Alog + d*DST + iq*4);
    float A0 = -__expf(al.x), A1 = -__expf(al.y), A2 = -__expf(al.z), A3 = -__expf(al.w);
    float P0=1.f,P1=1.f,P2=1.f,P3=1.f, S0=0.f,S1=0.f,S2=0.f,S3=0.f;
    for (int lt = 0; lt < nt; lt++) {
      float dtv = dtl[lt*DI + d];
      float du = dtv * xsc[lt*DI + d];
      float4 Bq = LD4(dbl + lt*36 + iq*4);
      float a0 = __expf(dtv*A0), a1 = __expf(dtv*A1), a2 = __expf(dtv*A2), a3 = __expf(dtv*A3);
      P0 *= a0; S0 = S0*a0 + du*Bq.x;
      P1 *= a1; S1 = S1*a1 + du*Bq.y;
      P2 *= a2; S2 = S2*a2 + du*Bq.z;
      P3 *= a3; S3 = S3*a3 + du*Bq.w;
    }
    size_t ob = (size_t)(sc*NCHUNK + c)*DI*DST + d*DST + iq*4;
    ST4(PRD + ob, make_float4(P0,P1,P2,P3));
    ST4(ACC + ob, make_float4(S0,S1,S2,S3));
  }
}

// ======== scan2: chunk-level scan; leaves per-chunk h_init in ACC ========
template<int DI>
__global__ __launch_bounds__(256) void scan2(const float* __restrict__ PRD, float* __restrict__ ACC, int nthread) {
  int tid = blockIdx.x*256 + threadIdx.x;
  if (tid >= nthread) return;
  int sc = tid / (DI*DST);
  int rem = tid - sc*(DI*DST);
  float h = 0.f;
  size_t idx = (size_t)sc*NCHUNK*DI*DST + rem;
  #pragma unroll 4
  for (int c = 0; c < NCHUNK; c++) {
    float p = PRD[idx];
    float s = ACC[idx];
    ACC[idx] = h;
    h = p*h + s;
    idx += (size_t)DI*DST;
  }
}

// ======== scan3p: scan + skip + gate + batched fused out_proj -> Y ========
// one block (64 threads, single wave) per (local seq, chunk); 8-token proj batches
template<int DM, int DI, int LT, int CL, int LSEQ>
__global__ __launch_bounds__(64) void scan3p(
    const float* __restrict__ XS, const float* __restrict__ DT,
    const float* __restrict__ Bb, const float* __restrict__ Cb,
    const float* __restrict__ GATE, const float* __restrict__ Alog,
    const float* __restrict__ Dp, const float* __restrict__ ACC,
    const float* __restrict__ wo, float* __restrict__ Y, int seq0)
{
  constexpr int DIP = DI + 4;   // pad to break stride-DI bank pattern
  __shared__ __align__(16) float wot[DM*DIP];
  __shared__ __align__(16) float gl[8*DI];
  int lane = threadIdx.x;
  for (int i = lane; i < DM*DI; i += 64) {
    int dm = i / DI, k = i - dm*DI;
    wot[dm*DIP + k] = wo[i];
  }
  int sc = blockIdx.x / NCHUNK, c = blockIdx.x % NCHUNK;
  int d = lane;
  float A[DST], h[DST];
  float Dd = 0.f;
  if (d < DI) {
    const float4* Ap = (const float4*)(Alog + d*DST);
    #pragma unroll
    for (int q = 0; q < 4; q++) {
      float4 av = Ap[q];
      A[q*4+0] = -__expf(av.x); A[q*4+1] = -__expf(av.y);
      A[q*4+2] = -__expf(av.z); A[q*4+3] = -__expf(av.w);
    }
    const float4* hp = (const float4*)(ACC + ((size_t)(sc*NCHUNK + c)*DI + d)*DST);
    #pragma unroll
    for (int q = 0; q < 4; q++) ((float4*)h)[q] = hp[q];
    Dd = Dp[d];
  }
  int t0 = c*CL, t1 = t0 + CL; if (t1 > LT) t1 = LT;
  size_t base = (size_t)sc*LT;
  size_t ybase = (size_t)(seq0 + sc)*LSEQ;
  int bt = 0, tstart = t0;
  __syncthreads();
  for (int t = t0; t < t1; t++) {
    if (d < DI) {
      size_t tb = base + t;
      float dtv = DT[tb*DI + d];
      float xsv = XS[tb*DI + d];
      float gv  = GATE[tb*DI + d];
      float du = dtv*xsv;
      float Bv[DST], Cv[DST];
      const float4* Bp = (const float4*)(Bb + tb*DST);
      const float4* Cp = (const float4*)(Cb + tb*DST);
      ((float4*)Bv)[0]=Bp[0]; ((float4*)Bv)[1]=Bp[1]; ((float4*)Bv)[2]=Bp[2]; ((float4*)Bv)[3]=Bp[3];
      ((float4*)Cv)[0]=Cp[0]; ((float4*)Cv)[1]=Cp[1]; ((float4*)Cv)[2]=Cp[2]; ((float4*)Cv)[3]=Cp[3];
      float y = 0.f;
      #pragma unroll
      for (int i = 0; i < DST; i++) {
        float a = __expf(dtv*A[i]);
        h[i] = h[i]*a + du*Bv[i];
        y += h[i]*Cv[i];
      }
      gl[bt*DI + d] = (y + xsv*Dd) * gv;
    }
    bt++;
    if (bt == 8 || t == t1 - 1) {
      __syncthreads();
      for (int o = lane; o < bt*DM; o += 64) {
        int b = o / DM, dm = o - b*DM;
        int tt = tstart + b;
        if (tt > 0) {
          float acc = 0.f;
          const float* gr = gl + b*DI;
          const float* wr = wot + dm*DIP;
          #pragma unroll
          for (int kq = 0; kq < DI/4; kq++) {
            float4 g4 = LD4(gr + kq*4);
            float4 w4 = LD4(wr + kq*4);
            acc += g4.x*w4.x + g4.y*w4.y + g4.z*w4.z + g4.w*w4.w;
          }
          Y[(ybase + tt - 1)*DM + dm] = acc;
        }
      }
      __syncthreads();
      bt = 0; tstart = t + 1;
    }
  }
}

// ======== fold: gather all three contributions, coalesced out write ========
__global__ __launch_bounds__(256) void fold_out(const float* __restrict__ Y0, const float* __restrict__ Y12,
                                                float* __restrict__ out) {
  int idx = blockIdx.x*256 + threadIdx.x;          // < 128*192*192
  int w = idx % W_;
  int h = (idx / W_) % H_;
  int c = idx / (W_*H_);
  int n = h / 3;
  int i = (h % 3)*8 + w/24;
  int j = w % 24;
  int p = 2*i + ((c>>1)&1);
  int q = 2*j + (c&1);
  float m0 = Y0[((size_t)n*L0 + p*48 + q)*DM0 + (c>>2)];
  float o1 = Y12[((size_t)n*L12 + c*24 + j)*DM2 + i];
  float o2 = Y12[((size_t)(64+n)*L12 + c*24 + i)*DM2 + j];
  out[idx] = (m0 + o1 + o2) * (1.f/3.f);
}

extern "C" void kernel_launch(void* const* d_in, const int* in_sizes, int n_in,
                              void* d_out, int out_size, void* d_ws, size_t ws_size,
                              hipStream_t stream) {
  const float* x       = (const float*)d_in[0];
  const float* norm_w  = (const float*)d_in[1];
  const float* norm_b  = (const float*)d_in[2];
  const float* norm2_w = (const float*)d_in[3];
  const float* norm2_b = (const float*)d_in[4];
  const float* gt1     = (const float*)d_in[5];
  const float* gt2     = (const float*)d_in[6];
  const float* m1_inw  = (const float*)d_in[7];
  const float* m1_cw   = (const float*)d_in[8];
  const float* m1_cb   = (const float*)d_in[9];
  const float* m1_xpw  = (const float*)d_in[10];
  const float* m1_dtw  = (const float*)d_in[11];
  const float* m1_dtb  = (const float*)d_in[12];
  const float* m1_alog = (const float*)d_in[13];
  const float* m1_D    = (const float*)d_in[14];
  const float* m1_ow   = (const float*)d_in[15];
  const float* m2_inw  = (const float*)d_in[16];
  const float* m2_cw   = (const float*)d_in[17];
  const float* m2_cb   = (const float*)d_in[18];
  const float* m2_xpw  = (const float*)d_in[19];
  const float* m2_dtw  = (const float*)d_in[20];
  const float* m2_dtb  = (const float*)d_in[21];
  const float* m2_alog = (const float*)d_in[22];
  const float* m2_D    = (const float*)d_in[23];
  const float* m2_ow   = (const float*)d_in[24];
  float* out = (float*)d_out;

  size_t wsf = ws_size / sizeof(float);

  // persistent projection buffers
  const size_t nY0  = (size_t)NS0*L0*DM0;    // 4,718,592
  const size_t nY12 = (size_t)NS12*L12*DM2;  // 9,437,184
  float* Y0  = (float*)d_ws;
  float* Y12 = Y0 + nY0;
  float* SCR = Y12 + nY12;
  size_t scrf = wsf - (nY0 + nY12);

  // ---- branch 0 (m1) ----
  {
    const size_t perState = (size_t)NCHUNK*DI0*DST;
    const size_t per = (size_t)LT0*(3*DI0 + 2*DST) + 2*perState;
    int cap = (int)(scrf / per); if (cap < 1) cap = 1; if (cap > NS0) cap = NS0;
    float* XS  = SCR;
    float* DT  = XS + (size_t)cap*LT0*DI0;
    float* Bb  = DT + (size_t)cap*LT0*DI0;
    float* Cb  = Bb + (size_t)cap*LT0*DST;
    float* GT  = Cb + (size_t)cap*LT0*DST;
    float* PRD = GT + (size_t)cap*LT0*DI0;
    float* ACC = PRD + (size_t)cap*perState;
    for (int s0 = 0; s0 < NS0; s0 += cap) {
      int cs = (NS0 - s0 < cap) ? (NS0 - s0) : cap;
      front<DM0, DI0, LT0, CL0, 0><<<cs*NCHUNK, 256, 0, stream>>>(
          x, gt1, norm_w, norm_b, m1_inw, m1_cw, m1_cb, m1_xpw, m1_dtw, m1_dtb,
          m1_alog, XS, DT, Bb, Cb, GT, PRD, ACC, s0);
      scan2<DI0><<<(cs*DI0*DST + 255)/256, 256, 0, stream>>>(PRD, ACC, cs*DI0*DST);
      scan3p<DM0, DI0, LT0, CL0, L0><<<cs*NCHUNK, 64, 0, stream>>>(
          XS, DT, Bb, Cb, GT, m1_alog, m1_D, ACC, m1_ow, Y0, s0);
    }
  }

  // ---- branches 1+2 (m2 shared weights; global seq id 0..127, branch = id>>6) ----
  {
    const size_t perState = (size_t)NCHUNK*DI2*DST;
    const size_t per = (size_t)LT12*(3*DI2 + 2*DST) + 2*perState;
    int cap = (int)(scrf / per); if (cap < 1) cap = 1; if (cap > NS12) cap = NS12;
    float* XS  = SCR;
    float* DT  = XS + (size_t)cap*LT12*DI2;
    float* Bb  = DT + (size_t)cap*LT12*DI2;
    float* Cb  = Bb + (size_t)cap*LT12*DST;
    float* GT  = Cb + (size_t)cap*LT12*DST;
    float* PRD = GT + (size_t)cap*LT12*DI2;
    float* ACC = PRD + (size_t)cap*perState;
    for (int s0 = 0; s0 < NS12; s0 += cap) {
      int cs = (NS12 - s0 < cap) ? (NS12 - s0) : cap;
      front<DM2, DI2, LT12, CL12, 1><<<cs*NCHUNK, 256, 0, stream>>>(
          x, gt2, norm2_w, norm2_b, m2_inw, m2_cw, m2_cb, m2_xpw, m2_dtw, m2_dtb,
          m2_alog, XS, DT, Bb, Cb, GT, PRD, ACC, s0);
      scan2<DI2><<<(cs*DI2*DST + 255)/256, 256, 0, stream>>>(PRD, ACC, cs*DI2*DST);
      scan3p<DM2, DI2, LT12, CL12, L12><<<cs*NCHUNK, 64, 0, stream>>>(
          XS, DT, Bb, Cb, GT, m2_alog, m2_D, ACC, m2_ow, Y12, s0);
    }
  }

  // ---- final fold ----
  fold_out<<<(C_*H_*W_)/256, 256, 0, stream>>>(Y0, Y12, out);
}

// Round 7
// 926.524 us; speedup vs baseline: 1.4904x; 1.4904x over previous
//
#include <hip/hip_runtime.h>
#include <math.h>

// Problem dims
#define H_   192
#define W_   192
#define C_   128
#define CS_  24

// branch 0 (m1)
#define DM0  32
#define DI0  64
#define L0   2304
#define LT0  2305
#define NS0  64

// branches 1+2 (m2, shared weights) run as 128 sequences
#define DM2  24
#define DI2  48
#define L12  3072
#define LT12 3073
#define NS12 128

#define DST  16
#define NCHUNK 64
#define CL0  ((LT0 + NCHUNK - 1) / NCHUNK)    // 37  (NR=40)
#define CL12 ((LT12 + NCHUNK - 1) / NCHUNK)   // 49  (NR=52)

__device__ __forceinline__ float sigmoidf_(float x){ return 1.f/(1.f+__expf(-x)); }
__device__ __forceinline__ float siluf_(float x){ return x*sigmoidf_(x); }
__device__ __forceinline__ float softplusf_(float x){ return (x > 20.f) ? x : log1pf(__expf(x)); }

#define LD4(p)  (*(const float4*)(p))
#define ST4(p,v) (*(float4*)(p) = (v))

// ======== front: gather+LN+in_proj+conv+silu+x_proj+dt+scan1-compose ========
// one block (256 thr) per (local seq, chunk). Scalar phases (low VGPR), 4 blocks/CU.
template<int DM, int DI, int LT, int CL, int BID>
__global__ __launch_bounds__(256) void front(
    const float* __restrict__ x, const float* __restrict__ gt,
    const float* __restrict__ nw, const float* __restrict__ nb,
    const float* __restrict__ win, const float* __restrict__ cw,
    const float* __restrict__ cb, const float* __restrict__ xpw,
    const float* __restrict__ dtw, const float* __restrict__ dtb,
    const float* __restrict__ Alog,
    float* __restrict__ XS, float* __restrict__ DT,
    float* __restrict__ Bb, float* __restrict__ Cb, float* __restrict__ GATE,
    float* __restrict__ PRD, float* __restrict__ ACC, int seq0)
{
  constexpr int NR  = CL + 3;                  // 40 / 52 (both %4 == 0)
  constexpr int R3A = DM*2*DI;                 // wint [k][col]
  constexpr int R3B = CL*36 + DI*34;           // dbl [CL][36] + xpwt [DI][34]
  constexpr int R3  = (R3A > R3B) ? R3A : R3B;
  __shared__ __align__(16) float smem[2*NR*DI + R3];
  float* xsin = smem;                          // [NR][DI]; phase5+: dtl overlay
  float* dtl  = smem;
  float* xsc  = smem + NR*DI;                  // [NR][DI]; phase1-2: xn [NR][DM]
  float* xn   = xsc;
  float* r3   = smem + 2*NR*DI;
  float* wint = r3;                            // [DM][2*DI] (k-major)
  float* dbl  = r3;                            // [CL][36]: B at 0..15, dt at 32,33
  float* xpwt = r3 + CL*36;                    // [DI][34]  (k-major)

  const int tid = threadIdx.x;
  const int sc = blockIdx.x / NCHUNK, c = blockIdx.x % NCHUNK;
  const int gid = seq0 + sc;
  const int t0 = c*CL;
  int nt = LT - t0; if (nt > CL) nt = CL;      // may be <= 0 for tail chunks

  // stage wint[k][col] = win[col*DM + k]
  for (int i = tid; i < DM*2*DI; i += 256) {
    int k = i / (2*DI), col = i - k*(2*DI);
    wint[i] = win[col*DM + k];
  }
  // phase 1: gather + LN -> xn (all NR rows; zero outside sequence)
  {
    int hw = tid >> 5, dm = tid & 31;
    for (int r = hw; r < NR; r += 8) {
      int t = t0 - 3 + r;
      bool inr = (t >= 0 && t < LT);
      float v = 0.f;
      if (inr && dm < DM) {
        if (t == 0) v = gt[dm];
        else {
          int s = t - 1;
          if (BID == 0) {
            int p = s / 48, q = s - p*48;
            int cc = dm*4 + (p&1)*2 + (q&1);
            int ii = p >> 1, jj = q >> 1;
            v = x[cc*(H_*W_) + ((gid>>3)*CS_ + ii)*W_ + (gid&7)*CS_ + jj];
          } else {
            int cc = s / 24, rr = s - cc*24;
            int n = gid & 63, br = gid >> 6;
            int ii = br ? rr : dm;
            int jj = br ? dm : rr;
            v = x[cc*(H_*W_) + ((n>>3)*CS_ + ii)*W_ + (n&7)*CS_ + jj];
          }
        }
      }
      float s1 = (dm < DM) ? v : 0.f;
      float s2 = s1*s1;
      #pragma unroll
      for (int off = 1; off < 32; off <<= 1) {
        s1 += __shfl_xor(s1, off);
        s2 += __shfl_xor(s2, off);
      }
      if (dm < DM) {
        float mean = s1 * (1.f/DM);
        float var = s2 * (1.f/DM) - mean*mean;
        float xv = (v - mean)*rsqrtf(var + 1e-5f)*nw[dm] + nb[dm];
        xn[r*DM + dm] = inr ? xv : 0.f;
      }
    }
  }
  __syncthreads();
  // phase 2: in_proj xs -> xsin ; z -> GATE = silu(z)
  for (int idx = tid; idx < (nt+3)*DI; idx += 256) {
    int r = idx / DI, d = idx - r*DI;
    float acc = 0.f;
    #pragma unroll
    for (int k = 0; k < DM; k++) acc += xn[r*DM + k]*wint[k*2*DI + d];
    xsin[idx] = acc;
  }
  for (int idx = tid; idx < nt*DI; idx += 256) {
    int lt = idx / DI, d = idx - lt*DI;
    int r = lt + 3;
    float acc = 0.f;
    #pragma unroll
    for (int k = 0; k < DM; k++) acc += xn[r*DM + k]*wint[k*2*DI + DI + d];
    GATE[((size_t)sc*LT + t0 + lt)*DI + d] = siluf_(acc);
  }
  __syncthreads();
  // phase 3: conv+silu -> xsc (+XS), zero-fill rows >= nt; stage xpwt
  for (int idx = tid; idx < NR*(DI/4); idx += 256) {
    int lt = idx / (DI/4), dq = idx - lt*(DI/4);
    int d0 = dq*4;
    float4 o = make_float4(0.f,0.f,0.f,0.f);
    if (lt < nt) {
      float4 a0 = LD4(xsin + (lt+0)*DI + d0);
      float4 a1 = LD4(xsin + (lt+1)*DI + d0);
      float4 a2 = LD4(xsin + (lt+2)*DI + d0);
      float4 a3 = LD4(xsin + (lt+3)*DI + d0);
      float4 w0 = LD4(cw + (d0+0)*4);
      float4 w1 = LD4(cw + (d0+1)*4);
      float4 w2 = LD4(cw + (d0+2)*4);
      float4 w3 = LD4(cw + (d0+3)*4);
      float4 cbq = LD4(cb + d0);
      o.x = siluf_(cbq.x + w0.x*a0.x + w0.y*a1.x + w0.z*a2.x + w0.w*a3.x);
      o.y = siluf_(cbq.y + w1.x*a0.y + w1.y*a1.y + w1.z*a2.y + w1.w*a3.y);
      o.z = siluf_(cbq.z + w2.x*a0.z + w2.y*a1.z + w2.z*a2.z + w2.w*a3.z);
      o.w = siluf_(cbq.w + w3.x*a0.w + w3.y*a1.w + w3.z*a2.w + w3.w*a3.w);
      ST4(XS + ((size_t)sc*LT + t0 + lt)*DI + d0, o);
    }
    ST4(xsc + lt*DI + d0, o);
  }
  for (int i = tid; i < DI*34; i += 256) {
    int k = i / 34, o = i - k*34;
    xpwt[i] = xpw[o*DI + k];
  }
  __syncthreads();
  // phase 4: x_proj -> dbl (B at 0..15, dt at 32,33) + Bb/Cb global
  for (int idx = tid; idx < nt*34; idx += 256) {
    int lt = idx / 34, o = idx - lt*34;
    float acc = 0.f;
    #pragma unroll
    for (int d = 0; d < DI; d++) acc += xsc[lt*DI + d]*xpwt[d*34 + o];
    size_t tb = (size_t)sc*LT + t0 + lt;
    if (o < 2)        dbl[lt*36 + 32 + o] = acc;
    else if (o < 18) { dbl[lt*36 + (o-2)] = acc; Bb[tb*DST + (o-2)] = acc; }
    else              Cb[tb*DST + (o-18)] = acc;
  }
  __syncthreads();
  // phase 5: dt -> dtl (overlays xsin) + DT
  for (int idx = tid; idx < nt*(DI/4); idx += 256) {
    int lt = idx / (DI/4), dq = idx - lt*(DI/4);
    int d0 = dq*4;
    float t0v = dbl[lt*36 + 32], t1v = dbl[lt*36 + 33];
    float4 w0 = LD4(dtw + 2*d0);
    float4 w1 = LD4(dtw + 2*d0 + 4);
    float4 b4 = LD4(dtb + d0);
    float4 r;
    r.x = softplusf_(t0v*w0.x + t1v*w0.y + b4.x);
    r.y = softplusf_(t0v*w0.z + t1v*w0.w + b4.y);
    r.z = softplusf_(t0v*w1.x + t1v*w1.y + b4.z);
    r.w = softplusf_(t0v*w1.z + t1v*w1.w + b4.w);
    ST4(dtl + lt*DI + d0, r);
    ST4(DT + ((size_t)sc*LT + t0 + lt)*DI + d0, r);
  }
  __syncthreads();
  // phase 6: chunk composition, thread = (d, state-quad); empty chunks emit P=1,S=0
  for (int p = tid; p < DI*4; p += 256) {
    int d = p >> 2, iq = p & 3;
    float4 al = LD4(Alog + d*DST + iq*4);
    float A0 = -__expf(al.x), A1 = -__expf(al.y), A2 = -__expf(al.z), A3 = -__expf(al.w);
    float P0=1.f,P1=1.f,P2=1.f,P3=1.f, S0=0.f,S1=0.f,S2=0.f,S3=0.f;
    for (int lt = 0; lt < nt; lt++) {
      float dtv = dtl[lt*DI + d];
      float du = dtv * xsc[lt*DI + d];
      float4 Bq = LD4(dbl + lt*36 + iq*4);
      float a0 = __expf(dtv*A0), a1 = __expf(dtv*A1), a2 = __expf(dtv*A2), a3 = __expf(dtv*A3);
      P0 *= a0; S0 = S0*a0 + du*Bq.x;
      P1 *= a1; S1 = S1*a1 + du*Bq.y;
      P2 *= a2; S2 = S2*a2 + du*Bq.z;
      P3 *= a3; S3 = S3*a3 + du*Bq.w;
    }
    size_t ob = (size_t)(sc*NCHUNK + c)*DI*DST + d*DST + iq*4;
    ST4(PRD + ob, make_float4(P0,P1,P2,P3));
    ST4(ACC + ob, make_float4(S0,S1,S2,S3));
  }
}

// ======== scan2: chunk-level scan; leaves per-chunk h_init in ACC ========
template<int DI>
__global__ __launch_bounds__(256) void scan2(const float* __restrict__ PRD, float* __restrict__ ACC, int nthread) {
  int tid = blockIdx.x*256 + threadIdx.x;
  if (tid >= nthread) return;
  int sc = tid / (DI*DST);
  int rem = tid - sc*(DI*DST);
  float h = 0.f;
  size_t idx = (size_t)sc*NCHUNK*DI*DST + rem;
  #pragma unroll 4
  for (int c = 0; c < NCHUNK; c++) {
    float p = PRD[idx];
    float s = ACC[idx];
    ACC[idx] = h;
    h = p*h + s;
    idx += (size_t)DI*DST;
  }
}

// ======== scan3p: scan + skip + gate + batched fused out_proj -> Y ========
// one block (64 threads, single wave) per (local seq, chunk); 8-token proj batches
template<int DM, int DI, int LT, int CL, int LSEQ>
__global__ __launch_bounds__(64) void scan3p(
    const float* __restrict__ XS, const float* __restrict__ DT,
    const float* __restrict__ Bb, const float* __restrict__ Cb,
    const float* __restrict__ GATE, const float* __restrict__ Alog,
    const float* __restrict__ Dp, const float* __restrict__ ACC,
    const float* __restrict__ wo, float* __restrict__ Y, int seq0)
{
  constexpr int DIP = DI + 4;   // pad to break stride-DI bank pattern
  __shared__ __align__(16) float wot[DM*DIP];
  __shared__ __align__(16) float gl[8*DI];
  int lane = threadIdx.x;
  for (int i = lane; i < DM*DI; i += 64) {
    int dm = i / DI, k = i - dm*DI;
    wot[dm*DIP + k] = wo[i];
  }
  int sc = blockIdx.x / NCHUNK, c = blockIdx.x % NCHUNK;
  int d = lane;
  float A[DST], h[DST];
  float Dd = 0.f;
  if (d < DI) {
    const float4* Ap = (const float4*)(Alog + d*DST);
    #pragma unroll
    for (int q = 0; q < 4; q++) {
      float4 av = Ap[q];
      A[q*4+0] = -__expf(av.x); A[q*4+1] = -__expf(av.y);
      A[q*4+2] = -__expf(av.z); A[q*4+3] = -__expf(av.w);
    }
    const float4* hp = (const float4*)(ACC + ((size_t)(sc*NCHUNK + c)*DI + d)*DST);
    #pragma unroll
    for (int q = 0; q < 4; q++) ((float4*)h)[q] = hp[q];
    Dd = Dp[d];
  }
  int t0 = c*CL, t1 = t0 + CL; if (t1 > LT) t1 = LT;
  size_t base = (size_t)sc*LT;
  size_t ybase = (size_t)(seq0 + sc)*LSEQ;
  int bt = 0, tstart = t0;
  __syncthreads();
  for (int t = t0; t < t1; t++) {
    if (d < DI) {
      size_t tb = base + t;
      float dtv = DT[tb*DI + d];
      float xsv = XS[tb*DI + d];
      float gv  = GATE[tb*DI + d];
      float du = dtv*xsv;
      float Bv[DST], Cv[DST];
      const float4* Bp = (const float4*)(Bb + tb*DST);
      const float4* Cp = (const float4*)(Cb + tb*DST);
      ((float4*)Bv)[0]=Bp[0]; ((float4*)Bv)[1]=Bp[1]; ((float4*)Bv)[2]=Bp[2]; ((float4*)Bv)[3]=Bp[3];
      ((float4*)Cv)[0]=Cp[0]; ((float4*)Cv)[1]=Cp[1]; ((float4*)Cv)[2]=Cp[2]; ((float4*)Cv)[3]=Cp[3];
      float y = 0.f;
      #pragma unroll
      for (int i = 0; i < DST; i++) {
        float a = __expf(dtv*A[i]);
        h[i] = h[i]*a + du*Bv[i];
        y += h[i]*Cv[i];
      }
      gl[bt*DI + d] = (y + xsv*Dd) * gv;
    }
    bt++;
    if (bt == 8 || t == t1 - 1) {
      __syncthreads();
      for (int o = lane; o < bt*DM; o += 64) {
        int b = o / DM, dm = o - b*DM;
        int tt = tstart + b;
        if (tt > 0) {
          float acc = 0.f;
          const float* gr = gl + b*DI;
          const float* wr = wot + dm*DIP;
          #pragma unroll
          for (int kq = 0; kq < DI/4; kq++) {
            float4 g4 = LD4(gr + kq*4);
            float4 w4 = LD4(wr + kq*4);
            acc += g4.x*w4.x + g4.y*w4.y + g4.z*w4.z + g4.w*w4.w;
          }
          Y[(ybase + tt - 1)*DM + dm] = acc;
        }
      }
      __syncthreads();
      bt = 0; tstart = t + 1;
    }
  }
}

// ======== fold: gather all three contributions, coalesced out write ========
__global__ __launch_bounds__(256) void fold_out(const float* __restrict__ Y0, const float* __restrict__ Y12,
                                                float* __restrict__ out) {
  int idx = blockIdx.x*256 + threadIdx.x;          // < 128*192*192
  int w = idx % W_;
  int h = (idx / W_) % H_;
  int c = idx / (W_*H_);
  int n = h / 3;
  int i = (h % 3)*8 + w/24;
  int j = w % 24;
  int p = 2*i + ((c>>1)&1);
  int q = 2*j + (c&1);
  float m0 = Y0[((size_t)n*L0 + p*48 + q)*DM0 + (c>>2)];
  float o1 = Y12[((size_t)n*L12 + c*24 + j)*DM2 + i];
  float o2 = Y12[((size_t)(64+n)*L12 + c*24 + i)*DM2 + j];
  out[idx] = (m0 + o1 + o2) * (1.f/3.f);
}

extern "C" void kernel_launch(void* const* d_in, const int* in_sizes, int n_in,
                              void* d_out, int out_size, void* d_ws, size_t ws_size,
                              hipStream_t stream) {
  const float* x       = (const float*)d_in[0];
  const float* norm_w  = (const float*)d_in[1];
  const float* norm_b  = (const float*)d_in[2];
  const float* norm2_w = (const float*)d_in[3];
  const float* norm2_b = (const float*)d_in[4];
  const float* gt1     = (const float*)d_in[5];
  const float* gt2     = (const float*)d_in[6];
  const float* m1_inw  = (const float*)d_in[7];
  const float* m1_cw   = (const float*)d_in[8];
  const float* m1_cb   = (const float*)d_in[9];
  const float* m1_xpw  = (const float*)d_in[10];
  const float* m1_dtw  = (const float*)d_in[11];
  const float* m1_dtb  = (const float*)d_in[12];
  const float* m1_alog = (const float*)d_in[13];
  const float* m1_D    = (const float*)d_in[14];
  const float* m1_ow   = (const float*)d_in[15];
  const float* m2_inw  = (const float*)d_in[16];
  const float* m2_cw   = (const float*)d_in[17];
  const float* m2_cb   = (const float*)d_in[18];
  const float* m2_xpw  = (const float*)d_in[19];
  const float* m2_dtw  = (const float*)d_in[20];
  const float* m2_dtb  = (const float*)d_in[21];
  const float* m2_alog = (const float*)d_in[22];
  const float* m2_D    = (const float*)d_in[23];
  const float* m2_ow   = (const float*)d_in[24];
  float* out = (float*)d_out;

  size_t wsf = ws_size / sizeof(float);

  // persistent projection buffers
  const size_t nY0  = (size_t)NS0*L0*DM0;    // 4,718,592
  const size_t nY12 = (size_t)NS12*L12*DM2;  // 9,437,184
  float* Y0  = (float*)d_ws;
  float* Y12 = Y0 + nY0;
  float* SCR = Y12 + nY12;
  size_t scrf = wsf - (nY0 + nY12);

  // ---- branch 0 (m1) ----
  {
    const size_t perState = (size_t)NCHUNK*DI0*DST;
    const size_t per = (size_t)LT0*(3*DI0 + 2*DST) + 2*perState;
    int cap = (int)(scrf / per); if (cap < 1) cap = 1; if (cap > NS0) cap = NS0;
    float* XS  = SCR;
    float* DT  = XS + (size_t)cap*LT0*DI0;
    float* Bb  = DT + (size_t)cap*LT0*DI0;
    float* Cb  = Bb + (size_t)cap*LT0*DST;
    float* GT  = Cb + (size_t)cap*LT0*DST;
    float* PRD = GT + (size_t)cap*LT0*DI0;
    float* ACC = PRD + (size_t)cap*perState;
    for (int s0 = 0; s0 < NS0; s0 += cap) {
      int cs = (NS0 - s0 < cap) ? (NS0 - s0) : cap;
      front<DM0, DI0, LT0, CL0, 0><<<cs*NCHUNK, 256, 0, stream>>>(
          x, gt1, norm_w, norm_b, m1_inw, m1_cw, m1_cb, m1_xpw, m1_dtw, m1_dtb,
          m1_alog, XS, DT, Bb, Cb, GT, PRD, ACC, s0);
      scan2<DI0><<<(cs*DI0*DST + 255)/256, 256, 0, stream>>>(PRD, ACC, cs*DI0*DST);
      scan3p<DM0, DI0, LT0, CL0, L0><<<cs*NCHUNK, 64, 0, stream>>>(
          XS, DT, Bb, Cb, GT, m1_alog, m1_D, ACC, m1_ow, Y0, s0);
    }
  }

  // ---- branches 1+2 (m2 shared weights; global seq id 0..127, branch = id>>6) ----
  {
    const size_t perState = (size_t)NCHUNK*DI2*DST;
    const size_t per = (size_t)LT12*(3*DI2 + 2*DST) + 2*perState;
    int cap = (int)(scrf / per); if (cap < 1) cap = 1; if (cap > NS12) cap = NS12;
    float* XS  = SCR;
    float* DT  = XS + (size_t)cap*LT12*DI2;
    float* Bb  = DT + (size_t)cap*LT12*DI2;
    float* Cb  = Bb + (size_t)cap*LT12*DST;
    float* GT  = Cb + (size_t)cap*LT12*DST;
    float* PRD = GT + (size_t)cap*LT12*DI2;
    float* ACC = PRD + (size_t)cap*perState;
    for (int s0 = 0; s0 < NS12; s0 += cap) {
      int cs = (NS12 - s0 < cap) ? (NS12 - s0) : cap;
      front<DM2, DI2, LT12, CL12, 1><<<cs*NCHUNK, 256, 0, stream>>>(
          x, gt2, norm2_w, norm2_b, m2_inw, m2_cw, m2_cb, m2_xpw, m2_dtw, m2_dtb,
          m2_alog, XS, DT, Bb, Cb, GT, PRD, ACC, s0);
      scan2<DI2><<<(cs*DI2*DST + 255)/256, 256, 0, stream>>>(PRD, ACC, cs*DI2*DST);
      scan3p<DM2, DI2, LT12, CL12, L12><<<cs*NCHUNK, 64, 0, stream>>>(
          XS, DT, Bb, Cb, GT, m2_alog, m2_D, ACC, m2_ow, Y12, s0);
    }
  }

  // ---- final fold ----
  fold_out<<<(C_*H_*W_)/256, 256, 0, stream>>>(Y0, Y12, out);
}